// Round 3
// baseline (846.923 us; speedup 1.0000x reference)
//
#include <hip/hip_runtime.h>
#include <hip/hip_bf16.h>
#include <math.h>

// Problem constants (fixed by setup_inputs)
#define BB 4
#define NN 16384
#define SS 4096
#define D1 128
#define D2 256
#define C1 256   // mlp[0]
#define C2 128   // mlp[1]
#define MTOT (BB*NN)   // 65536

// ---------------------------------------------------------------------------
// Pack xyz2 into float4 {x, y, z, ||p||^2} per point. pp uses the exact
// reference association order (contract off) so distances match bit-for-bit.
// ---------------------------------------------------------------------------
__global__ __launch_bounds__(256) void pack_kernel(
    const float* __restrict__ xyz2, float4* __restrict__ packed)
{
#pragma clang fp contract(off)
    int s = blockIdx.x * 256 + threadIdx.x;          // global over B*S
    float px = xyz2[s*3+0], py = xyz2[s*3+1], pz = xyz2[s*3+2];
    float pp = (px*px + py*py) + pz*pz;
    packed[s] = make_float4(px, py, pz, pp);
}

// ---------------------------------------------------------------------------
// 3-NN search. One block = 256 query points of one batch; packed xyz2[b]
// staged in LDS (64KB). Inner loop: wave-wide __any vote skips the top-3
// insertion (the loop-carried cndmask chain) on ~81% of candidates, making
// the common path dependency-free so unrolling yields real ILP at the 1
// wave/SIMD occupancy this grid gives. Distance formula matches the numpy
// reference bit-for-bit (contract off, same association order).
// ---------------------------------------------------------------------------
__global__ __launch_bounds__(256) void knn3_kernel(
    const float* __restrict__ xyz1, const float4* __restrict__ packed,
    int* __restrict__ idx_out, float* __restrict__ w_out)
{
#pragma clang fp contract(off)
    __shared__ float4 pk[SS];                        // 64 KB

    const int blocksPerB = NN / 256;                 // 64
    const int b = blockIdx.x / blocksPerB;
    const int chunk = blockIdx.x % blocksPerB;

    const float4* src = packed + (size_t)b * SS;
    for (int i = threadIdx.x; i < SS; i += 256) pk[i] = src[i];
    __syncthreads();

    const int n = chunk * 256 + threadIdx.x;
    const size_t m = (size_t)b * NN + n;
    const float qx = xyz1[m*3+0], qy = xyz1[m*3+1], qz = xyz1[m*3+2];
    const float qq = (qx*qx + qy*qy) + qz*qz;

    float d0 = 3.4e38f, d1 = 3.4e38f, d2v = 3.4e38f;
    int i0 = 0, i1 = 0, i2 = 0;

#pragma unroll 8
    for (int s = 0; s < SS; ++s) {
        float4 p = pk[s];
        float cr = (qx*p.x + qy*p.y) + qz*p.z;
        float d = (qq - 2.0f*cr) + p.w;
        d = fmaxf(d, 0.0f);
        if (__any(d < d2v)) {            // wave-uniform skip of insertion chain
            if (d < d2v) {
                if (d < d1) {
                    d2v = d1; i2 = i1;
                    if (d < d0) { d1 = d0; i1 = i0; d0 = d; i0 = s; }
                    else        { d1 = d;  i1 = s; }
                } else { d2v = d; i2 = s; }
            }
        }
    }

    float r0 = 1.0f / (d0  + 1e-8f);
    float r1 = 1.0f / (d1  + 1e-8f);
    float r2 = 1.0f / (d2v + 1e-8f);
    float z  = (r0 + r1) + r2;
    float inv = 1.0f / z;

    idx_out[m*3+0] = b * SS + i0;
    idx_out[m*3+1] = b * SS + i1;
    idx_out[m*3+2] = b * SS + i2;
    w_out[m*3+0] = r0 * inv;
    w_out[m*3+1] = r1 * inv;
    w_out[m*3+2] = r2 * inv;
}

// ---------------------------------------------------------------------------
// Tiled fp32 GEMM: C[M,N] = op(A[M,K]) @ W[N,K]^T (+ bias)
// op(A) optionally applies per-channel affine + relu (fused BN of prev layer).
// 64x64 tile, TK=16, 256 threads, 4x4 accum per thread.
// ---------------------------------------------------------------------------
template <bool BN_A>
__global__ __launch_bounds__(256) void gemm_kernel(
    const float* __restrict__ A, int lda,
    const float* __restrict__ W, int ldw,
    float* __restrict__ C, int ldc,
    int M, int N, int K,
    const float* __restrict__ bias,
    const float* __restrict__ scaleA,
    const float* __restrict__ shiftA)
{
    const int TM = 64, TN = 64, TK = 16;
    __shared__ float As[TK][TM + 4];
    __shared__ float Ws[TK][TN + 4];

    const int m0 = blockIdx.x * TM;
    const int n0 = blockIdx.y * TN;
    const int tid = threadIdx.x;
    const int tx = tid & 15;        // n dir
    const int ty = tid >> 4;        // m dir
    const int lr = tid >> 2;        // 0..63 load row
    const int lk = (tid & 3) * 4;   // 0,4,8,12 load k

    float acc[4][4] = {};

    for (int k0 = 0; k0 < K; k0 += TK) {
        float4 va = *(const float4*)(A + (size_t)(m0 + lr) * lda + k0 + lk);
        if (BN_A) {
            float4 sc = *(const float4*)(scaleA + k0 + lk);
            float4 sh = *(const float4*)(shiftA + k0 + lk);
            va.x = fmaxf(va.x * sc.x + sh.x, 0.0f);
            va.y = fmaxf(va.y * sc.y + sh.y, 0.0f);
            va.z = fmaxf(va.z * sc.z + sh.z, 0.0f);
            va.w = fmaxf(va.w * sc.w + sh.w, 0.0f);
        }
        float4 vw = *(const float4*)(W + (size_t)(n0 + lr) * ldw + k0 + lk);
        As[lk+0][lr] = va.x; As[lk+1][lr] = va.y; As[lk+2][lr] = va.z; As[lk+3][lr] = va.w;
        Ws[lk+0][lr] = vw.x; Ws[lk+1][lr] = vw.y; Ws[lk+2][lr] = vw.z; Ws[lk+3][lr] = vw.w;
        __syncthreads();

#pragma unroll
        for (int kk = 0; kk < TK; ++kk) {
            float a0 = As[kk][ty*4+0], a1 = As[kk][ty*4+1],
                  a2 = As[kk][ty*4+2], a3 = As[kk][ty*4+3];
            float b0 = Ws[kk][tx*4+0], b1 = Ws[kk][tx*4+1],
                  b2 = Ws[kk][tx*4+2], b3 = Ws[kk][tx*4+3];
            acc[0][0] += a0*b0; acc[0][1] += a0*b1; acc[0][2] += a0*b2; acc[0][3] += a0*b3;
            acc[1][0] += a1*b0; acc[1][1] += a1*b1; acc[1][2] += a1*b2; acc[1][3] += a1*b3;
            acc[2][0] += a2*b0; acc[2][1] += a2*b1; acc[2][2] += a2*b2; acc[2][3] += a2*b3;
            acc[3][0] += a3*b0; acc[3][1] += a3*b1; acc[3][2] += a3*b2; acc[3][3] += a3*b3;
        }
        __syncthreads();
    }

    float4 vb = make_float4(0.f, 0.f, 0.f, 0.f);
    if (bias) vb = *(const float4*)(bias + n0 + tx*4);
#pragma unroll
    for (int i = 0; i < 4; ++i) {
        float4 v;
        v.x = acc[i][0] + vb.x; v.y = acc[i][1] + vb.y;
        v.z = acc[i][2] + vb.z; v.w = acc[i][3] + vb.w;
        *(float4*)(C + (size_t)(m0 + ty*4 + i) * ldc + n0 + tx*4) = v;
    }
}

// ---------------------------------------------------------------------------
// y1[m, :] += sum_k w_k * P2[idx_k, :]   (interp contribution, post-GEMM)
// ---------------------------------------------------------------------------
__global__ __launch_bounds__(256) void interp_add_kernel(
    float* __restrict__ y1, const float* __restrict__ P2,
    const int* __restrict__ idx, const float* __restrict__ w)
{
    const int m = blockIdx.x;
    const int o = threadIdx.x;
    const int i0 = idx[m*3+0], i1 = idx[m*3+1], i2 = idx[m*3+2];
    const float w0 = w[m*3+0], w1 = w[m*3+1], w2 = w[m*3+2];
    float v = y1[(size_t)m*C1 + o];
    v += w0 * P2[(size_t)i0*C1 + o];
    v += w1 * P2[(size_t)i1*C1 + o];
    v += w2 * P2[(size_t)i2*C1 + o];
    y1[(size_t)m*C1 + o] = v;
}

// ---------------------------------------------------------------------------
// Per-channel sum / sumsq over rows (for batch-norm stats). C divides 256.
// ---------------------------------------------------------------------------
__global__ __launch_bounds__(256) void stats_kernel(
    const float* __restrict__ X, int M, int C,
    float* __restrict__ sum, float* __restrict__ sumsq)
{
    const int c = threadIdx.x & (C - 1);
    const int rsub = threadIdx.x / C;
    const int step = 256 / C;
    const int rowsPerBlock = M / gridDim.x;
    const int r0 = blockIdx.x * rowsPerBlock;
    float s = 0.f, s2 = 0.f;
    for (int r = r0 + rsub; r < r0 + rowsPerBlock; r += step) {
        float v = X[(size_t)r * C + c];
        s += v; s2 += v * v;
    }
    atomicAdd(&sum[c], s);
    atomicAdd(&sumsq[c], s2);
}

__global__ void finalize_kernel(
    const float* __restrict__ sum, const float* __restrict__ sumsq,
    const float* __restrict__ g, const float* __restrict__ beta,
    int M, int C, float* __restrict__ scale, float* __restrict__ shift)
{
    int c = threadIdx.x;
    if (c >= C) return;
    float invM = 1.0f / (float)M;
    float mean = sum[c] * invM;
    float var = fmaxf(sumsq[c] * invM - mean * mean, 0.0f);
    float rstd = 1.0f / sqrtf(var + 1e-5f);
    float sc = g[c] * rstd;
    scale[c] = sc;
    shift[c] = beta[c] - mean * sc;
}

__global__ __launch_bounds__(256) void bnrelu_kernel(
    float* __restrict__ X, int total, int C,
    const float* __restrict__ scale, const float* __restrict__ shift)
{
    int i = blockIdx.x * 256 + threadIdx.x;
    if (i >= total) return;
    int c = i & (C - 1);
    X[i] = fmaxf(X[i] * scale[c] + shift[c], 0.0f);
}

// ---------------------------------------------------------------------------
extern "C" void kernel_launch(void* const* d_in, const int* in_sizes, int n_in,
                              void* d_out, int out_size, void* d_ws, size_t ws_size,
                              hipStream_t stream) {
    const float* xyz1    = (const float*)d_in[0];
    const float* xyz2    = (const float*)d_in[1];
    const float* points1 = (const float*)d_in[2];
    const float* points2 = (const float*)d_in[3];
    const float* W1      = (const float*)d_in[4];
    const float* b1      = (const float*)d_in[5];
    const float* g1      = (const float*)d_in[6];
    const float* beta1   = (const float*)d_in[7];
    const float* W2      = (const float*)d_in[8];
    const float* b2      = (const float*)d_in[9];
    const float* g2      = (const float*)d_in[10];
    const float* beta2   = (const float*)d_in[11];
    float* out = (float*)d_out;

    // ws layout (floats; all offsets 16B-aligned)
    char* ws = (char*)d_ws;
    int*   idx = (int*)ws;                                 // MTOT*3 ints
    float* w   = (float*)(ws + (size_t)MTOT*3*4);          // MTOT*3 floats
    float* P2  = (float*)(ws + (size_t)MTOT*6*4);          // B*S*C1
    float* y1  = P2 + (size_t)BB*SS*C1;                    // MTOT*C1
    float* stats = y1 + (size_t)MTOT*C1;                   // 2048 floats reserved
    float* sum1 = stats;            // 256
    float* sq1  = stats + 256;      // 256
    float* sum2 = stats + 512;      // 128
    float* sq2  = stats + 640;      // 128
    float* scale1 = stats + 768;    // 256
    float* shift1 = stats + 1024;   // 256
    float* scale2 = stats + 1280;   // 128
    float* shift2 = stats + 1408;   // 128
    float4* packed = (float4*)(stats + 2048);              // B*S float4 (1MB)

    hipMemsetAsync(stats, 0, 768 * sizeof(float), stream);

    // 0) pack xyz2 -> {x,y,z,pp}
    pack_kernel<<<(BB*SS)/256, 256, 0, stream>>>(xyz2, packed);

    // 1) 3-NN + weights
    knn3_kernel<<<BB * (NN/256), 256, 0, stream>>>(xyz1, packed, idx, w);

    // 2) P2 = points2 @ W1[:,128:]^T   [B*S, 256]
    gemm_kernel<false><<<dim3((BB*SS)/64, C1/64), 256, 0, stream>>>(
        points2, D2, W1 + D1, D1 + D2, P2, C1, BB*SS, C1, D2,
        nullptr, nullptr, nullptr);

    // 3) y1 = points1 @ W1[:,:128]^T + b1   [M, 256]
    gemm_kernel<false><<<dim3(MTOT/64, C1/64), 256, 0, stream>>>(
        points1, D1, W1, D1 + D2, y1, C1, MTOT, C1, D1,
        b1, nullptr, nullptr);

    // 4) y1 += interp (weighted gather of P2 rows)
    interp_add_kernel<<<MTOT, 256, 0, stream>>>(y1, P2, idx, w);

    // 5) BN1 stats -> scale1/shift1
    stats_kernel<<<512, 256, 0, stream>>>(y1, MTOT, C1, sum1, sq1);
    finalize_kernel<<<1, 256, 0, stream>>>(sum1, sq1, g1, beta1, MTOT, C1, scale1, shift1);

    // 6) y2 = relu(bn1(y1)) @ W2^T + b2 -> d_out (pre-activation)
    gemm_kernel<true><<<dim3(MTOT/64, C2/64), 256, 0, stream>>>(
        y1, C1, W2, C1, out, C2, MTOT, C2, C1,
        b2, scale1, shift1);

    // 7) BN2 stats -> scale2/shift2; apply in place
    stats_kernel<<<512, 256, 0, stream>>>(out, MTOT, C2, sum2, sq2);
    finalize_kernel<<<1, 128, 0, stream>>>(sum2, sq2, g2, beta2, MTOT, C2, scale2, shift2);
    bnrelu_kernel<<<(MTOT*C2)/256, 256, 0, stream>>>(out, MTOT*C2, C2, scale2, shift2);
}

// Round 4
// 612.561 us; speedup vs baseline: 1.3826x; 1.3826x over previous
//
#include <hip/hip_runtime.h>
#include <hip/hip_bf16.h>
#include <math.h>

// Problem constants (fixed by setup_inputs)
#define BB 4
#define NN 16384
#define SS 4096
#define D1 128
#define D2 256
#define C1 256   // mlp[0]
#define C2 128   // mlp[1]
#define MTOT (BB*NN)   // 65536

// knn decomposition
#define QPT 2              // queries per thread
#define SCH 1024           // candidates per chunk (16KB LDS)
#define NCH (SS/SCH)       // 4 chunks

// ---------------------------------------------------------------------------
// Pack xyz2 into float4 {x, y, z, ||p||^2} per point. pp uses the exact
// reference association order (contract off) so distances match bit-for-bit.
// ---------------------------------------------------------------------------
__global__ __launch_bounds__(256) void pack_kernel(
    const float* __restrict__ xyz2, float4* __restrict__ packed)
{
#pragma clang fp contract(off)
    int s = blockIdx.x * 256 + threadIdx.x;          // global over B*S
    float px = xyz2[s*3+0], py = xyz2[s*3+1], pz = xyz2[s*3+2];
    float pp = (px*px + py*py) + pz*pz;
    packed[s] = make_float4(px, py, pz, pp);
}

// ---------------------------------------------------------------------------
// 3-NN pass 1: per (query, candidate-chunk) top-3 with BRANCH-FREE insertion
// (3 v_cmp + 10 v_cndmask, no exec-mask branches). 2 queries/thread give the
// carried min-chain ILP and halve LDS traffic per query. Distance formula
// matches the numpy reference bit-for-bit (contract off, same association).
// Strict '<' keeps the earliest candidate on ties (stable like lax.top_k).
// ---------------------------------------------------------------------------
__global__ __launch_bounds__(256) void knn3_partial_kernel(
    const float* __restrict__ xyz1, const float4* __restrict__ packed,
    float* __restrict__ pdist, int* __restrict__ pidx)
{
#pragma clang fp contract(off)
    __shared__ float4 pk[SCH];                       // 16 KB

    const int qblocks = NN / (256 * QPT);            // 32
    const int b  = blockIdx.x / (qblocks * NCH);
    const int r  = blockIdx.x % (qblocks * NCH);
    const int qc = r / NCH;
    const int sc = r % NCH;

    const float4* src = packed + (size_t)b * SS + sc * SCH;
    for (int i = threadIdx.x; i < SCH; i += 256) pk[i] = src[i];
    __syncthreads();

    float qx[QPT], qy[QPT], qz[QPT], qq[QPT];
    float e0[QPT], e1[QPT], e2[QPT];
    int   j0[QPT], j1[QPT], j2[QPT];
#pragma unroll
    for (int q = 0; q < QPT; ++q) {
        int n = qc * (256 * QPT) + q * 256 + threadIdx.x;
        size_t m = (size_t)b * NN + n;
        qx[q] = xyz1[m*3+0]; qy[q] = xyz1[m*3+1]; qz[q] = xyz1[m*3+2];
        qq[q] = (qx[q]*qx[q] + qy[q]*qy[q]) + qz[q]*qz[q];
        e0[q] = 3.4e38f; e1[q] = 3.4e38f; e2[q] = 3.4e38f;
        j0[q] = 0; j1[q] = 0; j2[q] = 0;
    }

#pragma unroll 4
    for (int s = 0; s < SCH; ++s) {
        float4 p = pk[s];
#pragma unroll
        for (int q = 0; q < QPT; ++q) {
            float cr = (qx[q]*p.x + qy[q]*p.y) + qz[q]*p.z;
            float d = (qq[q] - 2.0f*cr) + p.w;
            d = fmaxf(d, 0.0f);
            bool c0 = d < e0[q], c1 = d < e1[q], c2 = d < e2[q];
            e2[q] = c1 ? e1[q] : (c2 ? d : e2[q]);
            j2[q] = c1 ? j1[q] : (c2 ? s : j2[q]);
            e1[q] = c0 ? e0[q] : (c1 ? d : e1[q]);
            j1[q] = c0 ? j0[q] : (c1 ? s : j1[q]);
            e0[q] = c0 ? d : e0[q];
            j0[q] = c0 ? s : j0[q];
        }
    }

#pragma unroll
    for (int q = 0; q < QPT; ++q) {
        int n = qc * (256 * QPT) + q * 256 + threadIdx.x;
        size_t m = (size_t)b * NN + n;
        size_t base = (m * NCH + sc) * 3;
        pdist[base+0] = e0[q]; pdist[base+1] = e1[q]; pdist[base+2] = e2[q];
        pidx [base+0] = sc*SCH + j0[q];
        pidx [base+1] = sc*SCH + j1[q];
        pidx [base+2] = sc*SCH + j2[q];
    }
}

// ---------------------------------------------------------------------------
// 3-NN pass 2: merge the NCH partial (sorted) triples per query in ascending
// chunk order with strict '<' -> preserves reference stable tie order.
// Emits final global idx + normalized weights.
// ---------------------------------------------------------------------------
__global__ __launch_bounds__(256) void knn3_merge_kernel(
    const float* __restrict__ pdist, const int* __restrict__ pidx,
    int* __restrict__ idx_out, float* __restrict__ w_out)
{
#pragma clang fp contract(off)
    int m = blockIdx.x * 256 + threadIdx.x;
    int b = m / NN;
    size_t base = (size_t)m * NCH * 3;
    float d0 = pdist[base+0], d1 = pdist[base+1], d2 = pdist[base+2];
    int   i0 = pidx [base+0], i1 = pidx [base+1], i2 = pidx [base+2];
#pragma unroll
    for (int c = 1; c < NCH; ++c) {
#pragma unroll
        for (int j = 0; j < 3; ++j) {
            float d = pdist[base + c*3 + j];
            int   s = pidx [base + c*3 + j];
            bool c0 = d < d0, c1 = d < d1, c2 = d < d2;
            d2 = c1 ? d1 : (c2 ? d : d2);  i2 = c1 ? i1 : (c2 ? s : i2);
            d1 = c0 ? d0 : (c1 ? d : d1);  i1 = c0 ? i0 : (c1 ? s : i1);
            d0 = c0 ? d : d0;              i0 = c0 ? s : i0;
        }
    }
    float r0 = 1.0f / (d0 + 1e-8f);
    float r1 = 1.0f / (d1 + 1e-8f);
    float r2 = 1.0f / (d2 + 1e-8f);
    float z  = (r0 + r1) + r2;
    float inv = 1.0f / z;
    idx_out[m*3+0] = b * SS + i0;
    idx_out[m*3+1] = b * SS + i1;
    idx_out[m*3+2] = b * SS + i2;
    w_out[m*3+0] = r0 * inv;
    w_out[m*3+1] = r1 * inv;
    w_out[m*3+2] = r2 * inv;
}

// ---------------------------------------------------------------------------
// Tiled fp32 GEMM: C[M,N] = op(A[M,K]) @ W[N,K]^T (+ bias)
// op(A) optionally applies per-channel affine + relu (fused BN of prev layer).
// 64x64 tile, TK=16, 256 threads, 4x4 accum per thread.
// ---------------------------------------------------------------------------
template <bool BN_A>
__global__ __launch_bounds__(256) void gemm_kernel(
    const float* __restrict__ A, int lda,
    const float* __restrict__ W, int ldw,
    float* __restrict__ C, int ldc,
    int M, int N, int K,
    const float* __restrict__ bias,
    const float* __restrict__ scaleA,
    const float* __restrict__ shiftA)
{
    const int TM = 64, TN = 64, TK = 16;
    __shared__ float As[TK][TM + 4];
    __shared__ float Ws[TK][TN + 4];

    const int m0 = blockIdx.x * TM;
    const int n0 = blockIdx.y * TN;
    const int tid = threadIdx.x;
    const int tx = tid & 15;        // n dir
    const int ty = tid >> 4;        // m dir
    const int lr = tid >> 2;        // 0..63 load row
    const int lk = (tid & 3) * 4;   // 0,4,8,12 load k

    float acc[4][4] = {};

    for (int k0 = 0; k0 < K; k0 += TK) {
        float4 va = *(const float4*)(A + (size_t)(m0 + lr) * lda + k0 + lk);
        if (BN_A) {
            float4 sc = *(const float4*)(scaleA + k0 + lk);
            float4 sh = *(const float4*)(shiftA + k0 + lk);
            va.x = fmaxf(va.x * sc.x + sh.x, 0.0f);
            va.y = fmaxf(va.y * sc.y + sh.y, 0.0f);
            va.z = fmaxf(va.z * sc.z + sh.z, 0.0f);
            va.w = fmaxf(va.w * sc.w + sh.w, 0.0f);
        }
        float4 vw = *(const float4*)(W + (size_t)(n0 + lr) * ldw + k0 + lk);
        As[lk+0][lr] = va.x; As[lk+1][lr] = va.y; As[lk+2][lr] = va.z; As[lk+3][lr] = va.w;
        Ws[lk+0][lr] = vw.x; Ws[lk+1][lr] = vw.y; Ws[lk+2][lr] = vw.z; Ws[lk+3][lr] = vw.w;
        __syncthreads();

#pragma unroll
        for (int kk = 0; kk < TK; ++kk) {
            float a0 = As[kk][ty*4+0], a1 = As[kk][ty*4+1],
                  a2 = As[kk][ty*4+2], a3 = As[kk][ty*4+3];
            float b0 = Ws[kk][tx*4+0], b1 = Ws[kk][tx*4+1],
                  b2 = Ws[kk][tx*4+2], b3 = Ws[kk][tx*4+3];
            acc[0][0] += a0*b0; acc[0][1] += a0*b1; acc[0][2] += a0*b2; acc[0][3] += a0*b3;
            acc[1][0] += a1*b0; acc[1][1] += a1*b1; acc[1][2] += a1*b2; acc[1][3] += a1*b3;
            acc[2][0] += a2*b0; acc[2][1] += a2*b1; acc[2][2] += a2*b2; acc[2][3] += a2*b3;
            acc[3][0] += a3*b0; acc[3][1] += a3*b1; acc[3][2] += a3*b2; acc[3][3] += a3*b3;
        }
        __syncthreads();
    }

    float4 vb = make_float4(0.f, 0.f, 0.f, 0.f);
    if (bias) vb = *(const float4*)(bias + n0 + tx*4);
#pragma unroll
    for (int i = 0; i < 4; ++i) {
        float4 v;
        v.x = acc[i][0] + vb.x; v.y = acc[i][1] + vb.y;
        v.z = acc[i][2] + vb.z; v.w = acc[i][3] + vb.w;
        *(float4*)(C + (size_t)(m0 + ty*4 + i) * ldc + n0 + tx*4) = v;
    }
}

// ---------------------------------------------------------------------------
// y1[m, :] += sum_k w_k * P2[idx_k, :]   (interp contribution, post-GEMM)
// ---------------------------------------------------------------------------
__global__ __launch_bounds__(256) void interp_add_kernel(
    float* __restrict__ y1, const float* __restrict__ P2,
    const int* __restrict__ idx, const float* __restrict__ w)
{
    const int m = blockIdx.x;
    const int o = threadIdx.x;
    const int i0 = idx[m*3+0], i1 = idx[m*3+1], i2 = idx[m*3+2];
    const float w0 = w[m*3+0], w1 = w[m*3+1], w2 = w[m*3+2];
    float v = y1[(size_t)m*C1 + o];
    v += w0 * P2[(size_t)i0*C1 + o];
    v += w1 * P2[(size_t)i1*C1 + o];
    v += w2 * P2[(size_t)i2*C1 + o];
    y1[(size_t)m*C1 + o] = v;
}

// ---------------------------------------------------------------------------
// Per-channel sum / sumsq over rows (for batch-norm stats). C divides 256.
// ---------------------------------------------------------------------------
__global__ __launch_bounds__(256) void stats_kernel(
    const float* __restrict__ X, int M, int C,
    float* __restrict__ sum, float* __restrict__ sumsq)
{
    const int c = threadIdx.x & (C - 1);
    const int rsub = threadIdx.x / C;
    const int step = 256 / C;
    const int rowsPerBlock = M / gridDim.x;
    const int r0 = blockIdx.x * rowsPerBlock;
    float s = 0.f, s2 = 0.f;
    for (int r = r0 + rsub; r < r0 + rowsPerBlock; r += step) {
        float v = X[(size_t)r * C + c];
        s += v; s2 += v * v;
    }
    atomicAdd(&sum[c], s);
    atomicAdd(&sumsq[c], s2);
}

__global__ void finalize_kernel(
    const float* __restrict__ sum, const float* __restrict__ sumsq,
    const float* __restrict__ g, const float* __restrict__ beta,
    int M, int C, float* __restrict__ scale, float* __restrict__ shift)
{
    int c = threadIdx.x;
    if (c >= C) return;
    float invM = 1.0f / (float)M;
    float mean = sum[c] * invM;
    float var = fmaxf(sumsq[c] * invM - mean * mean, 0.0f);
    float rstd = 1.0f / sqrtf(var + 1e-5f);
    float sc = g[c] * rstd;
    scale[c] = sc;
    shift[c] = beta[c] - mean * sc;
}

__global__ __launch_bounds__(256) void bnrelu_kernel(
    float* __restrict__ X, int total, int C,
    const float* __restrict__ scale, const float* __restrict__ shift)
{
    int i = blockIdx.x * 256 + threadIdx.x;
    if (i >= total) return;
    int c = i & (C - 1);
    X[i] = fmaxf(X[i] * scale[c] + shift[c], 0.0f);
}

// ---------------------------------------------------------------------------
extern "C" void kernel_launch(void* const* d_in, const int* in_sizes, int n_in,
                              void* d_out, int out_size, void* d_ws, size_t ws_size,
                              hipStream_t stream) {
    const float* xyz1    = (const float*)d_in[0];
    const float* xyz2    = (const float*)d_in[1];
    const float* points1 = (const float*)d_in[2];
    const float* points2 = (const float*)d_in[3];
    const float* W1      = (const float*)d_in[4];
    const float* b1      = (const float*)d_in[5];
    const float* g1      = (const float*)d_in[6];
    const float* beta1   = (const float*)d_in[7];
    const float* W2      = (const float*)d_in[8];
    const float* b2      = (const float*)d_in[9];
    const float* g2      = (const float*)d_in[10];
    const float* beta2   = (const float*)d_in[11];
    float* out = (float*)d_out;

    // ws layout (floats; all offsets 16B-aligned)
    char* ws = (char*)d_ws;
    int*   idx = (int*)ws;                                 // MTOT*3 ints
    float* w   = (float*)(ws + (size_t)MTOT*3*4);          // MTOT*3 floats
    float* P2  = (float*)(ws + (size_t)MTOT*6*4);          // B*S*C1
    float* y1  = P2 + (size_t)BB*SS*C1;                    // MTOT*C1
    float* stats = y1 + (size_t)MTOT*C1;                   // 2048 floats reserved
    float* sum1 = stats;            // 256
    float* sq1  = stats + 256;      // 256
    float* sum2 = stats + 512;      // 128
    float* sq2  = stats + 640;      // 128
    float* scale1 = stats + 768;    // 256
    float* shift1 = stats + 1024;   // 256
    float* scale2 = stats + 1280;   // 128
    float* shift2 = stats + 1408;   // 128
    float4* packed = (float4*)(stats + 2048);              // B*S float4 (1MB)

    // knn partials alias the y1 region (y1 is only written later, in stream
    // order, by the step-3 GEMM — safe reuse, no extra ws).
    float* pdist = y1;                                     // MTOT*NCH*3 floats
    int*   pidx  = (int*)(y1 + (size_t)MTOT*NCH*3);        // MTOT*NCH*3 ints

    hipMemsetAsync(stats, 0, 768 * sizeof(float), stream);

    // 0) pack xyz2 -> {x,y,z,pp}
    pack_kernel<<<(BB*SS)/256, 256, 0, stream>>>(xyz2, packed);

    // 1) 3-NN: partial top-3 per chunk, then merge -> idx + weights
    knn3_partial_kernel<<<BB * (NN/(256*QPT)) * NCH, 256, 0, stream>>>(
        xyz1, packed, pdist, pidx);
    knn3_merge_kernel<<<MTOT/256, 256, 0, stream>>>(pdist, pidx, idx, w);

    // 2) P2 = points2 @ W1[:,128:]^T   [B*S, 256]
    gemm_kernel<false><<<dim3((BB*SS)/64, C1/64), 256, 0, stream>>>(
        points2, D2, W1 + D1, D1 + D2, P2, C1, BB*SS, C1, D2,
        nullptr, nullptr, nullptr);

    // 3) y1 = points1 @ W1[:,:128]^T + b1   [M, 256]
    gemm_kernel<false><<<dim3(MTOT/64, C1/64), 256, 0, stream>>>(
        points1, D1, W1, D1 + D2, y1, C1, MTOT, C1, D1,
        b1, nullptr, nullptr);

    // 4) y1 += interp (weighted gather of P2 rows)
    interp_add_kernel<<<MTOT, 256, 0, stream>>>(y1, P2, idx, w);

    // 5) BN1 stats -> scale1/shift1
    stats_kernel<<<512, 256, 0, stream>>>(y1, MTOT, C1, sum1, sq1);
    finalize_kernel<<<1, 256, 0, stream>>>(sum1, sq1, g1, beta1, MTOT, C1, scale1, shift1);

    // 6) y2 = relu(bn1(y1)) @ W2^T + b2 -> d_out (pre-activation)
    gemm_kernel<true><<<dim3(MTOT/64, C2/64), 256, 0, stream>>>(
        y1, C1, W2, C1, out, C2, MTOT, C2, C1,
        b2, scale1, shift1);

    // 7) BN2 stats -> scale2/shift2; apply in place
    stats_kernel<<<512, 256, 0, stream>>>(out, MTOT, C2, sum2, sq2);
    finalize_kernel<<<1, 128, 0, stream>>>(sum2, sq2, g2, beta2, MTOT, C2, scale2, shift2);
    bnrelu_kernel<<<(MTOT*C2)/256, 256, 0, stream>>>(out, MTOT*C2, C2, scale2, shift2);
}

// Round 5
// 526.657 us; speedup vs baseline: 1.6081x; 1.1631x over previous
//
#include <hip/hip_runtime.h>
#include <hip/hip_bf16.h>
#include <math.h>

// Problem constants (fixed by setup_inputs)
#define BB 4
#define NN 16384
#define SS 4096
#define D1 128
#define D2 256
#define C1 256   // mlp[0]
#define C2 128   // mlp[1]
#define MTOT (BB*NN)   // 65536

// knn decomposition
#define QPT 2              // queries per thread
#define SCH 1024           // candidates per chunk (16KB LDS)
#define NCH (SS/SCH)       // 4 chunks

// MFMA types (per cdna_hip_programming.md §3, compile-verified recipe)
typedef short bf16x8 __attribute__((ext_vector_type(8)));
typedef float f32x4  __attribute__((ext_vector_type(4)));

#define LPAD 40            // LDS row stride in bf16 elems (80B, 16B-aligned)

__device__ inline unsigned short f2bf(float x) {
    unsigned u = __builtin_bit_cast(unsigned, x);
    unsigned r = u + 0x7FFFu + ((u >> 16) & 1u);
    return (unsigned short)(r >> 16);
}
__device__ inline float bf2f(unsigned short h) {
    unsigned u = ((unsigned)h) << 16;
    return __builtin_bit_cast(float, u);
}

// ---------------------------------------------------------------------------
// Pack xyz2 into float4 {x, y, z, ||p||^2} (exact reference association).
// ---------------------------------------------------------------------------
__global__ __launch_bounds__(256) void pack_kernel(
    const float* __restrict__ xyz2, float4* __restrict__ packed)
{
#pragma clang fp contract(off)
    int s = blockIdx.x * 256 + threadIdx.x;
    float px = xyz2[s*3+0], py = xyz2[s*3+1], pz = xyz2[s*3+2];
    float pp = (px*px + py*py) + pz*pz;
    packed[s] = make_float4(px, py, pz, pp);
}

// ---------------------------------------------------------------------------
// Split W1, W2 into hi/lo bf16 (fp32 = hi + lo to ~2^-18 rel).
// ---------------------------------------------------------------------------
__global__ __launch_bounds__(256) void wsplit_kernel(
    const float* __restrict__ W1, const float* __restrict__ W2,
    unsigned short* __restrict__ W1h, unsigned short* __restrict__ W1l,
    unsigned short* __restrict__ W2h, unsigned short* __restrict__ W2l)
{
    int i = blockIdx.x * 256 + threadIdx.x;
    if (i < C1 * (D1 + D2)) {
        float x = W1[i];
        unsigned short h = f2bf(x);
        W1h[i] = h; W1l[i] = f2bf(x - bf2f(h));
    }
    if (i < C2 * C1) {
        float x = W2[i];
        unsigned short h = f2bf(x);
        W2h[i] = h; W2l[i] = f2bf(x - bf2f(h));
    }
}

// ---------------------------------------------------------------------------
// 3-NN pass 1: branch-free per-chunk top-3 (unchanged from round 4 — passed).
// ---------------------------------------------------------------------------
__global__ __launch_bounds__(256) void knn3_partial_kernel(
    const float* __restrict__ xyz1, const float4* __restrict__ packed,
    float* __restrict__ pdist, int* __restrict__ pidx)
{
#pragma clang fp contract(off)
    __shared__ float4 pk[SCH];

    const int qblocks = NN / (256 * QPT);
    const int b  = blockIdx.x / (qblocks * NCH);
    const int r  = blockIdx.x % (qblocks * NCH);
    const int qc = r / NCH;
    const int sc = r % NCH;

    const float4* src = packed + (size_t)b * SS + sc * SCH;
    for (int i = threadIdx.x; i < SCH; i += 256) pk[i] = src[i];
    __syncthreads();

    float qx[QPT], qy[QPT], qz[QPT], qq[QPT];
    float e0[QPT], e1[QPT], e2[QPT];
    int   j0[QPT], j1[QPT], j2[QPT];
#pragma unroll
    for (int q = 0; q < QPT; ++q) {
        int n = qc * (256 * QPT) + q * 256 + threadIdx.x;
        size_t m = (size_t)b * NN + n;
        qx[q] = xyz1[m*3+0]; qy[q] = xyz1[m*3+1]; qz[q] = xyz1[m*3+2];
        qq[q] = (qx[q]*qx[q] + qy[q]*qy[q]) + qz[q]*qz[q];
        e0[q] = 3.4e38f; e1[q] = 3.4e38f; e2[q] = 3.4e38f;
        j0[q] = 0; j1[q] = 0; j2[q] = 0;
    }

#pragma unroll 4
    for (int s = 0; s < SCH; ++s) {
        float4 p = pk[s];
#pragma unroll
        for (int q = 0; q < QPT; ++q) {
            float cr = (qx[q]*p.x + qy[q]*p.y) + qz[q]*p.z;
            float d = (qq[q] - 2.0f*cr) + p.w;
            d = fmaxf(d, 0.0f);
            bool c0 = d < e0[q], c1 = d < e1[q], c2 = d < e2[q];
            e2[q] = c1 ? e1[q] : (c2 ? d : e2[q]);
            j2[q] = c1 ? j1[q] : (c2 ? s : j2[q]);
            e1[q] = c0 ? e0[q] : (c1 ? d : e1[q]);
            j1[q] = c0 ? j0[q] : (c1 ? s : j1[q]);
            e0[q] = c0 ? d : e0[q];
            j0[q] = c0 ? s : j0[q];
        }
    }

#pragma unroll
    for (int q = 0; q < QPT; ++q) {
        int n = qc * (256 * QPT) + q * 256 + threadIdx.x;
        size_t m = (size_t)b * NN + n;
        size_t base = (m * NCH + sc) * 3;
        pdist[base+0] = e0[q]; pdist[base+1] = e1[q]; pdist[base+2] = e2[q];
        pidx [base+0] = sc*SCH + j0[q];
        pidx [base+1] = sc*SCH + j1[q];
        pidx [base+2] = sc*SCH + j2[q];
    }
}

// ---------------------------------------------------------------------------
// 3-NN pass 2: merge chunk triples (ascending chunk order, strict '<').
// ---------------------------------------------------------------------------
__global__ __launch_bounds__(256) void knn3_merge_kernel(
    const float* __restrict__ pdist, const int* __restrict__ pidx,
    int* __restrict__ idx_out, float* __restrict__ w_out)
{
#pragma clang fp contract(off)
    int m = blockIdx.x * 256 + threadIdx.x;
    int b = m / NN;
    size_t base = (size_t)m * NCH * 3;
    float d0 = pdist[base+0], d1 = pdist[base+1], d2 = pdist[base+2];
    int   i0 = pidx [base+0], i1 = pidx [base+1], i2 = pidx [base+2];
#pragma unroll
    for (int c = 1; c < NCH; ++c) {
#pragma unroll
        for (int j = 0; j < 3; ++j) {
            float d = pdist[base + c*3 + j];
            int   s = pidx [base + c*3 + j];
            bool c0 = d < d0, c1 = d < d1, c2 = d < d2;
            d2 = c1 ? d1 : (c2 ? d : d2);  i2 = c1 ? i1 : (c2 ? s : i2);
            d1 = c0 ? d0 : (c1 ? d : d1);  i1 = c0 ? i0 : (c1 ? s : i1);
            d0 = c0 ? d : d0;              i0 = c0 ? s : i0;
        }
    }
    float r0 = 1.0f / (d0 + 1e-8f);
    float r1 = 1.0f / (d1 + 1e-8f);
    float r2 = 1.0f / (d2 + 1e-8f);
    float z  = (r0 + r1) + r2;
    float inv = 1.0f / z;
    idx_out[m*3+0] = b * SS + i0;
    idx_out[m*3+1] = b * SS + i1;
    idx_out[m*3+2] = b * SS + i2;
    w_out[m*3+0] = r0 * inv;
    w_out[m*3+1] = r1 * inv;
    w_out[m*3+2] = r2 * inv;
}

// ---------------------------------------------------------------------------
// Split-bf16 MFMA GEMM: C[M x N] = op(A[M x K]) @ W[N x K]^T + bias
//   fp32 accuracy via A=Ah+Al, B=Bh+Bl; D += Ah·Bh + Al·Bh + Ah·Bl.
// Tile 64(M) x 128(N), 4 waves of 32x64, k-chunk 32 (16x16x32 bf16 MFMA).
// Optional fused: BN+ReLU on A-load; interp gather add; BN-stats atomics.
// ---------------------------------------------------------------------------
template<int K, bool BN_A, bool FUSE_INTERP, bool FUSE_STATS>
__global__ __launch_bounds__(256, 4) void gemm_mfma_kernel(
    const float* __restrict__ A, int lda,
    const unsigned short* __restrict__ Wh, const unsigned short* __restrict__ Wl, int ldw,
    float* __restrict__ C, int ldc,
    const float* __restrict__ bias,
    const float* __restrict__ scaleA, const float* __restrict__ shiftA,
    const float* __restrict__ P2, const int* __restrict__ idx3, const float* __restrict__ w3,
    float* __restrict__ sumO, float* __restrict__ sqO)
{
    __shared__ unsigned short Ash[64 * LPAD];
    __shared__ unsigned short Asl[64 * LPAD];
    __shared__ unsigned short Bsh[128 * LPAD];
    __shared__ unsigned short Bsl[128 * LPAD];

    const int tid = threadIdx.x;
    const int m0 = blockIdx.x * 64;
    const int n0 = blockIdx.y * 128;
    const int wave = tid >> 6, lane = tid & 63;
    const int ln = lane & 15, q4 = lane >> 4;
    const int wm = wave & 1, wn = wave >> 1;

    const int ar = tid >> 2, ak = (tid & 3) * 8;   // A staging: 64 rows x 32k, 8/thread
    const int br = tid >> 1, bk = (tid & 1) * 16;  // B staging: 128 rows x 32k, 16/thread

    f32x4 acc[2][4] = {};                          // [mi][ni]

    for (int k0 = 0; k0 < K; k0 += 32) {
        // ---- stage A: fp32 load, optional BN+ReLU, split to hi/lo bf16 ----
        const float* ap = A + (size_t)(m0 + ar) * lda + k0 + ak;
        float av[8];
        *(float4*)&av[0] = *(const float4*)ap;
        *(float4*)&av[4] = *(const float4*)(ap + 4);
        if (BN_A) {
#pragma unroll
            for (int i = 0; i < 8; ++i) {
                float sc = scaleA[k0 + ak + i];
                float sh = shiftA[k0 + ak + i];
                av[i] = fmaxf(av[i] * sc + sh, 0.0f);
            }
        }
        bf16x8 vh, vl;
#pragma unroll
        for (int i = 0; i < 8; ++i) {
            unsigned short h = f2bf(av[i]);
            vh[i] = (short)h;
            vl[i] = (short)f2bf(av[i] - bf2f(h));
        }
        *(bf16x8*)&Ash[ar * LPAD + ak] = vh;
        *(bf16x8*)&Asl[ar * LPAD + ak] = vl;

        // ---- stage B: pre-split bf16 direct copy ----
        {
            const unsigned short* bph = Wh + (size_t)(n0 + br) * ldw + k0 + bk;
            const unsigned short* bpl = Wl + (size_t)(n0 + br) * ldw + k0 + bk;
            *(bf16x8*)&Bsh[br * LPAD + bk]     = *(const bf16x8*)bph;
            *(bf16x8*)&Bsh[br * LPAD + bk + 8] = *(const bf16x8*)(bph + 8);
            *(bf16x8*)&Bsl[br * LPAD + bk]     = *(const bf16x8*)bpl;
            *(bf16x8*)&Bsl[br * LPAD + bk + 8] = *(const bf16x8*)(bpl + 8);
        }
        __syncthreads();

        // ---- fragments + MFMA ----
        bf16x8 afh[2], afl[2];
#pragma unroll
        for (int mi = 0; mi < 2; ++mi) {
            int arow = wm * 32 + mi * 16 + ln;
            afh[mi] = *(const bf16x8*)&Ash[arow * LPAD + q4 * 8];
            afl[mi] = *(const bf16x8*)&Asl[arow * LPAD + q4 * 8];
        }
        bf16x8 bfh[4], bfl[4];
#pragma unroll
        for (int ni = 0; ni < 4; ++ni) {
            int brow = wn * 64 + ni * 16 + ln;
            bfh[ni] = *(const bf16x8*)&Bsh[brow * LPAD + q4 * 8];
            bfl[ni] = *(const bf16x8*)&Bsl[brow * LPAD + q4 * 8];
        }
#pragma unroll
        for (int mi = 0; mi < 2; ++mi) {
#pragma unroll
            for (int ni = 0; ni < 4; ++ni) {
                acc[mi][ni] = __builtin_amdgcn_mfma_f32_16x16x32_bf16(afh[mi], bfh[ni], acc[mi][ni], 0, 0, 0);
                acc[mi][ni] = __builtin_amdgcn_mfma_f32_16x16x32_bf16(afl[mi], bfh[ni], acc[mi][ni], 0, 0, 0);
                acc[mi][ni] = __builtin_amdgcn_mfma_f32_16x16x32_bf16(afh[mi], bfl[ni], acc[mi][ni], 0, 0, 0);
            }
        }
        __syncthreads();
    }

    // ---- epilogue: interp add (into acc), bias, store, stats atomics ----
    // C/D layout: col = ln, row = q4*4 + r  (verified m89/m91)
    if (FUSE_INTERP) {
#pragma unroll
        for (int mi = 0; mi < 2; ++mi) {
#pragma unroll
            for (int r = 0; r < 4; ++r) {
                int row_g = m0 + wm * 32 + mi * 16 + q4 * 4 + r;
                const int*   ip = idx3 + (size_t)row_g * 3;
                const float* wp = w3   + (size_t)row_g * 3;
                int   ia = ip[0], ib = ip[1], ic = ip[2];
                float wa = wp[0], wb = wp[1], wc = wp[2];
#pragma unroll
                for (int ni = 0; ni < 4; ++ni) {
                    int col = n0 + wn * 64 + ni * 16 + ln;
                    acc[mi][ni][r] += wa * P2[(size_t)ia * C1 + col]
                                    + wb * P2[(size_t)ib * C1 + col]
                                    + wc * P2[(size_t)ic * C1 + col];
                }
            }
        }
    }

#pragma unroll
    for (int ni = 0; ni < 4; ++ni) {
        int col = n0 + wn * 64 + ni * 16 + ln;
        float vb = bias ? bias[col] : 0.0f;
        float s = 0.0f, s2 = 0.0f;
#pragma unroll
        for (int mi = 0; mi < 2; ++mi) {
#pragma unroll
            for (int r = 0; r < 4; ++r) {
                int row_g = m0 + wm * 32 + mi * 16 + q4 * 4 + r;
                float v = acc[mi][ni][r] + vb;
                C[(size_t)row_g * ldc + col] = v;
                s += v; s2 += v * v;
            }
        }
        if (FUSE_STATS) {
            s  += __shfl_xor(s, 16);  s  += __shfl_xor(s, 32);
            s2 += __shfl_xor(s2, 16); s2 += __shfl_xor(s2, 32);
            if (q4 == 0) {
                atomicAdd(&sumO[col], s);
                atomicAdd(&sqO[col], s2);
            }
        }
    }
}

// ---------------------------------------------------------------------------
__global__ void finalize_kernel(
    const float* __restrict__ sum, const float* __restrict__ sumsq,
    const float* __restrict__ g, const float* __restrict__ beta,
    int M, int C, float* __restrict__ scale, float* __restrict__ shift)
{
    int c = threadIdx.x;
    if (c >= C) return;
    float invM = 1.0f / (float)M;
    float mean = sum[c] * invM;
    float var = fmaxf(sumsq[c] * invM - mean * mean, 0.0f);
    float rstd = 1.0f / sqrtf(var + 1e-5f);
    float sc = g[c] * rstd;
    scale[c] = sc;
    shift[c] = beta[c] - mean * sc;
}

__global__ __launch_bounds__(256) void bnrelu_kernel(
    float* __restrict__ X, int total, int C,
    const float* __restrict__ scale, const float* __restrict__ shift)
{
    int i = blockIdx.x * 256 + threadIdx.x;
    if (i >= total) return;
    int c = i & (C - 1);
    X[i] = fmaxf(X[i] * scale[c] + shift[c], 0.0f);
}

// ---------------------------------------------------------------------------
extern "C" void kernel_launch(void* const* d_in, const int* in_sizes, int n_in,
                              void* d_out, int out_size, void* d_ws, size_t ws_size,
                              hipStream_t stream) {
    const float* xyz1    = (const float*)d_in[0];
    const float* xyz2    = (const float*)d_in[1];
    const float* points1 = (const float*)d_in[2];
    const float* points2 = (const float*)d_in[3];
    const float* W1      = (const float*)d_in[4];
    const float* b1      = (const float*)d_in[5];
    const float* g1      = (const float*)d_in[6];
    const float* beta1   = (const float*)d_in[7];
    const float* W2      = (const float*)d_in[8];
    const float* b2      = (const float*)d_in[9];
    const float* g2      = (const float*)d_in[10];
    const float* beta2   = (const float*)d_in[11];
    float* out = (float*)d_out;

    // ws layout (16B-aligned chunks)
    char* ws = (char*)d_ws;
    int*   idx = (int*)ws;                                 // MTOT*3
    float* w   = (float*)(ws + (size_t)MTOT*3*4);          // MTOT*3
    float* P2  = (float*)(ws + (size_t)MTOT*6*4);          // B*S*C1
    float* y1  = P2 + (size_t)BB*SS*C1;                    // MTOT*C1
    float* stats = y1 + (size_t)MTOT*C1;                   // 2048 floats
    float* sum1 = stats;            // 256
    float* sq1  = stats + 256;      // 256
    float* sum2 = stats + 512;      // 128
    float* sq2  = stats + 640;      // 128
    float* scale1 = stats + 768;    // 256
    float* shift1 = stats + 1024;   // 256
    float* scale2 = stats + 1280;   // 128
    float* shift2 = stats + 1408;   // 128
    float4* packed = (float4*)(stats + 2048);              // B*S float4
    unsigned short* W1h = (unsigned short*)(packed + (size_t)BB*SS);
    unsigned short* W1l = W1h + (size_t)C1*(D1+D2);
    unsigned short* W2h = W1l + (size_t)C1*(D1+D2);
    unsigned short* W2l = W2h + (size_t)C2*C1;

    // knn partials alias y1 (y1 written later in stream order)
    float* pdist = y1;                                     // MTOT*NCH*3
    int*   pidx  = (int*)(y1 + (size_t)MTOT*NCH*3);        // MTOT*NCH*3

    hipMemsetAsync(stats, 0, 768 * sizeof(float), stream);

    pack_kernel<<<(BB*SS)/256, 256, 0, stream>>>(xyz2, packed);
    wsplit_kernel<<<(C1*(D1+D2))/256, 256, 0, stream>>>(W1, W2, W1h, W1l, W2h, W2l);

    knn3_partial_kernel<<<BB * (NN/(256*QPT)) * NCH, 256, 0, stream>>>(
        xyz1, packed, pdist, pidx);
    knn3_merge_kernel<<<MTOT/256, 256, 0, stream>>>(pdist, pidx, idx, w);

    // P2 = points2 @ W1[:,128:]^T   [B*S x 256], K=256
    gemm_mfma_kernel<256, false, false, false><<<dim3((BB*SS)/64, C1/128), 256, 0, stream>>>(
        points2, D2, W1h + D1, W1l + D1, D1 + D2, P2, C1,
        nullptr, nullptr, nullptr, nullptr, nullptr, nullptr, nullptr, nullptr);

    // y1 = points1 @ W1[:,:128]^T + b1 + interp;  fused BN1 stats
    gemm_mfma_kernel<128, false, true, true><<<dim3(MTOT/64, C1/128), 256, 0, stream>>>(
        points1, D1, W1h, W1l, D1 + D2, y1, C1,
        b1, nullptr, nullptr, P2, idx, w, sum1, sq1);

    finalize_kernel<<<1, 256, 0, stream>>>(sum1, sq1, g1, beta1, MTOT, C1, scale1, shift1);

    // out = relu(bn1(y1)) @ W2^T + b2;  fused BN2 stats
    gemm_mfma_kernel<256, true, false, true><<<dim3(MTOT/64, C2/128), 256, 0, stream>>>(
        y1, C1, W2h, W2l, C1, out, C2,
        b2, scale1, shift1, nullptr, nullptr, nullptr, sum2, sq2);

    finalize_kernel<<<1, 128, 0, stream>>>(sum2, sq2, g2, beta2, MTOT, C2, scale2, shift2);
    bnrelu_kernel<<<(MTOT*C2)/256, 256, 0, stream>>>(out, MTOT*C2, C2, scale2, shift2);
}

// Round 6
// 503.574 us; speedup vs baseline: 1.6818x; 1.0458x over previous
//
#include <hip/hip_runtime.h>
#include <hip/hip_bf16.h>
#include <math.h>

// Problem constants (fixed by setup_inputs)
#define BB 4
#define NN 16384
#define SS 4096
#define D1 128
#define D2 256
#define C1 256   // mlp[0]
#define C2 128   // mlp[1]
#define MTOT (BB*NN)   // 65536

// knn decomposition
#define QPT 2              // queries per thread
#define SCH 512            // candidates per chunk (8KB LDS -> 4 waves/SIMD)
#define NCH (SS/SCH)       // 8 chunks

typedef _Float16 f16x8 __attribute__((ext_vector_type(8)));
typedef float f32x4  __attribute__((ext_vector_type(4)));

#define LPAD 40            // LDS row stride in fp16 elems (80B, 16B-aligned)

// ---------------------------------------------------------------------------
// Pack xyz2 into float4 {x, y, z, ||p||^2} (exact reference association).
// ---------------------------------------------------------------------------
__global__ __launch_bounds__(256) void pack_kernel(
    const float* __restrict__ xyz2, float4* __restrict__ packed)
{
#pragma clang fp contract(off)
    int s = blockIdx.x * 256 + threadIdx.x;
    float px = xyz2[s*3+0], py = xyz2[s*3+1], pz = xyz2[s*3+2];
    float pp = (px*px + py*py) + pz*pz;
    packed[s] = make_float4(px, py, pz, pp);
}

// ---------------------------------------------------------------------------
// Convert W1, W2 to fp16 (RNE) once.
// ---------------------------------------------------------------------------
__global__ __launch_bounds__(256) void wcvt_kernel(
    const float* __restrict__ W1, const float* __restrict__ W2,
    _Float16* __restrict__ W1c, _Float16* __restrict__ W2c)
{
    int i = blockIdx.x * 256 + threadIdx.x;
    if (i < C1 * (D1 + D2)) W1c[i] = (_Float16)W1[i];
    if (i < C2 * C1)        W2c[i] = (_Float16)W2[i];
}

// ---------------------------------------------------------------------------
// 3-NN pass 1: branch-free per-chunk top-3. Distance triple via min/med3
// (provably identical to the cndmask chain); index tracking via cndmask from
// pre-update comparisons. Distance formula matches the reference bit-for-bit
// (contract off, same association order). Strict '<' keeps earliest on ties.
// ---------------------------------------------------------------------------
__global__ __launch_bounds__(256) void knn3_partial_kernel(
    const float* __restrict__ xyz1, const float4* __restrict__ packed,
    float* __restrict__ pdist, int* __restrict__ pidx)
{
#pragma clang fp contract(off)
    __shared__ float4 pk[SCH];                       // 8 KB

    const int qblocks = NN / (256 * QPT);            // 32
    const int b  = blockIdx.x / (qblocks * NCH);
    const int r  = blockIdx.x % (qblocks * NCH);
    const int qc = r / NCH;
    const int sc = r % NCH;

    const float4* src = packed + (size_t)b * SS + sc * SCH;
    for (int i = threadIdx.x; i < SCH; i += 256) pk[i] = src[i];
    __syncthreads();

    float qx[QPT], qy[QPT], qz[QPT], qq[QPT];
    float e0[QPT], e1[QPT], e2[QPT];
    int   j0[QPT], j1[QPT], j2[QPT];
#pragma unroll
    for (int q = 0; q < QPT; ++q) {
        int n = qc * (256 * QPT) + q * 256 + threadIdx.x;
        size_t m = (size_t)b * NN + n;
        qx[q] = xyz1[m*3+0]; qy[q] = xyz1[m*3+1]; qz[q] = xyz1[m*3+2];
        qq[q] = (qx[q]*qx[q] + qy[q]*qy[q]) + qz[q]*qz[q];
        e0[q] = 3.4e38f; e1[q] = 3.4e38f; e2[q] = 3.4e38f;
        j0[q] = 0; j1[q] = 0; j2[q] = 0;
    }

#pragma unroll 4
    for (int s = 0; s < SCH; ++s) {
        float4 p = pk[s];
#pragma unroll
        for (int q = 0; q < QPT; ++q) {
            float cr = (qx[q]*p.x + qy[q]*p.y) + qz[q]*p.z;
            float d = (qq[q] - 2.0f*cr) + p.w;
            d = fmaxf(d, 0.0f);
            bool c0 = d < e0[q], c1 = d < e1[q], c2 = d < e2[q];
            j2[q] = c1 ? j1[q] : (c2 ? s : j2[q]);
            j1[q] = c0 ? j0[q] : (c1 ? s : j1[q]);
            j0[q] = c0 ? s : j0[q];
            e2[q] = __builtin_amdgcn_fmed3f(e1[q], d, e2[q]);
            e1[q] = __builtin_amdgcn_fmed3f(e0[q], d, e1[q]);
            e0[q] = fminf(e0[q], d);
        }
    }

#pragma unroll
    for (int q = 0; q < QPT; ++q) {
        int n = qc * (256 * QPT) + q * 256 + threadIdx.x;
        size_t m = (size_t)b * NN + n;
        size_t base = (m * NCH + sc) * 3;
        pdist[base+0] = e0[q]; pdist[base+1] = e1[q]; pdist[base+2] = e2[q];
        pidx [base+0] = sc*SCH + j0[q];
        pidx [base+1] = sc*SCH + j1[q];
        pidx [base+2] = sc*SCH + j2[q];
    }
}

// ---------------------------------------------------------------------------
// 3-NN pass 2: merge chunk triples (ascending chunk order, strict '<').
// ---------------------------------------------------------------------------
__global__ __launch_bounds__(256) void knn3_merge_kernel(
    const float* __restrict__ pdist, const int* __restrict__ pidx,
    int* __restrict__ idx_out, float* __restrict__ w_out)
{
#pragma clang fp contract(off)
    int m = blockIdx.x * 256 + threadIdx.x;
    int b = m / NN;
    size_t base = (size_t)m * NCH * 3;
    float d0 = pdist[base+0], d1 = pdist[base+1], d2 = pdist[base+2];
    int   i0 = pidx [base+0], i1 = pidx [base+1], i2 = pidx [base+2];
#pragma unroll
    for (int c = 1; c < NCH; ++c) {
#pragma unroll
        for (int j = 0; j < 3; ++j) {
            float d = pdist[base + c*3 + j];
            int   s = pidx [base + c*3 + j];
            bool c0 = d < d0, c1 = d < d1, c2 = d < d2;
            d2 = c1 ? d1 : (c2 ? d : d2);  i2 = c1 ? i1 : (c2 ? s : i2);
            d1 = c0 ? d0 : (c1 ? d : d1);  i1 = c0 ? i0 : (c1 ? s : i1);
            d0 = c0 ? d : d0;              i0 = c0 ? s : i0;
        }
    }
    float r0 = 1.0f / (d0 + 1e-8f);
    float r1 = 1.0f / (d1 + 1e-8f);
    float r2 = 1.0f / (d2 + 1e-8f);
    float z  = (r0 + r1) + r2;
    float inv = 1.0f / z;
    idx_out[m*3+0] = b * SS + i0;
    idx_out[m*3+1] = b * SS + i1;
    idx_out[m*3+2] = b * SS + i2;
    w_out[m*3+0] = r0 * inv;
    w_out[m*3+1] = r1 * inv;
    w_out[m*3+2] = r2 * inv;
}

// ---------------------------------------------------------------------------
// fp16 MFMA GEMM: C[M x N] = op(A[M x K]) @ W[N x K]^T + bias
// A converted fp32->fp16 on the fly (1 cvt/elem); W pre-converted.
// Tile 64(M) x 128(N), 4 waves of 32x64, k-chunk 32 (16x16x32 f16 MFMA).
// Optional fused: BN+ReLU on A-load; interp gather add; BN-stats atomics.
// fp16 product error ~2^-11, fp32 accumulate -> absmax contribution ~1e-3/row.
// ---------------------------------------------------------------------------
template<int K, bool BN_A, bool FUSE_INTERP, bool FUSE_STATS>
__global__ __launch_bounds__(256, 4) void gemm_mfma_kernel(
    const float* __restrict__ A, int lda,
    const _Float16* __restrict__ W, int ldw,
    float* __restrict__ C, int ldc,
    const float* __restrict__ bias,
    const float* __restrict__ scaleA, const float* __restrict__ shiftA,
    const float* __restrict__ P2, const int* __restrict__ idx3, const float* __restrict__ w3,
    float* __restrict__ sumO, float* __restrict__ sqO)
{
    __shared__ _Float16 Ash[64 * LPAD];     // 5 KB
    __shared__ _Float16 Bsh[128 * LPAD];    // 10 KB

    const int tid = threadIdx.x;
    const int m0 = blockIdx.x * 64;
    const int n0 = blockIdx.y * 128;
    const int wave = tid >> 6, lane = tid & 63;
    const int ln = lane & 15, q4 = lane >> 4;
    const int wm = wave & 1, wn = wave >> 1;

    const int ar = tid >> 2, ak = (tid & 3) * 8;   // A staging: 64 rows x 32k
    const int br = tid >> 1, bk = (tid & 1) * 16;  // B staging: 128 rows x 32k

    f32x4 acc[2][4] = {};                          // [mi][ni]

    for (int k0 = 0; k0 < K; k0 += 32) {
        // ---- stage A: fp32 load, optional BN+ReLU, cvt fp16 ----
        const float* ap = A + (size_t)(m0 + ar) * lda + k0 + ak;
        float av[8];
        *(float4*)&av[0] = *(const float4*)ap;
        *(float4*)&av[4] = *(const float4*)(ap + 4);
        if (BN_A) {
#pragma unroll
            for (int i = 0; i < 8; ++i) {
                float sc = scaleA[k0 + ak + i];
                float sh = shiftA[k0 + ak + i];
                av[i] = fmaxf(av[i] * sc + sh, 0.0f);
            }
        }
        f16x8 vh;
#pragma unroll
        for (int i = 0; i < 8; ++i) vh[i] = (_Float16)av[i];
        *(f16x8*)&Ash[ar * LPAD + ak] = vh;

        // ---- stage B: pre-converted fp16 direct copy ----
        {
            const _Float16* bp = W + (size_t)(n0 + br) * ldw + k0 + bk;
            *(f16x8*)&Bsh[br * LPAD + bk]     = *(const f16x8*)bp;
            *(f16x8*)&Bsh[br * LPAD + bk + 8] = *(const f16x8*)(bp + 8);
        }
        __syncthreads();

        // ---- fragments + MFMA ----
        f16x8 af[2];
#pragma unroll
        for (int mi = 0; mi < 2; ++mi) {
            int arow = wm * 32 + mi * 16 + ln;
            af[mi] = *(const f16x8*)&Ash[arow * LPAD + q4 * 8];
        }
        f16x8 bf[4];
#pragma unroll
        for (int ni = 0; ni < 4; ++ni) {
            int brow = wn * 64 + ni * 16 + ln;
            bf[ni] = *(const f16x8*)&Bsh[brow * LPAD + q4 * 8];
        }
#pragma unroll
        for (int mi = 0; mi < 2; ++mi)
#pragma unroll
            for (int ni = 0; ni < 4; ++ni)
                acc[mi][ni] = __builtin_amdgcn_mfma_f32_16x16x32_f16(af[mi], bf[ni], acc[mi][ni], 0, 0, 0);
        __syncthreads();
    }

    // ---- epilogue ----  C/D layout: col = ln, row = q4*4 + r  (m89/m91)
    if (FUSE_INTERP) {
#pragma unroll
        for (int mi = 0; mi < 2; ++mi) {
#pragma unroll
            for (int r = 0; r < 4; ++r) {
                int row_g = m0 + wm * 32 + mi * 16 + q4 * 4 + r;
                const int*   ip = idx3 + (size_t)row_g * 3;
                const float* wp = w3   + (size_t)row_g * 3;
                int   ia = ip[0], ib = ip[1], ic = ip[2];
                float wa = wp[0], wb = wp[1], wc = wp[2];
#pragma unroll
                for (int ni = 0; ni < 4; ++ni) {
                    int col = n0 + wn * 64 + ni * 16 + ln;
                    acc[mi][ni][r] += wa * P2[(size_t)ia * C1 + col]
                                    + wb * P2[(size_t)ib * C1 + col]
                                    + wc * P2[(size_t)ic * C1 + col];
                }
            }
        }
    }

#pragma unroll
    for (int ni = 0; ni < 4; ++ni) {
        int col = n0 + wn * 64 + ni * 16 + ln;
        float vb = bias ? bias[col] : 0.0f;
        float s = 0.0f, s2 = 0.0f;
#pragma unroll
        for (int mi = 0; mi < 2; ++mi) {
#pragma unroll
            for (int r = 0; r < 4; ++r) {
                int row_g = m0 + wm * 32 + mi * 16 + q4 * 4 + r;
                float v = acc[mi][ni][r] + vb;
                C[(size_t)row_g * ldc + col] = v;
                s += v; s2 += v * v;
            }
        }
        if (FUSE_STATS) {
            s  += __shfl_xor(s, 16);  s  += __shfl_xor(s, 32);
            s2 += __shfl_xor(s2, 16); s2 += __shfl_xor(s2, 32);
            if (q4 == 0) {
                atomicAdd(&sumO[col], s);
                atomicAdd(&sqO[col], s2);
            }
        }
    }
}

// ---------------------------------------------------------------------------
__global__ void finalize_kernel(
    const float* __restrict__ sum, const float* __restrict__ sumsq,
    const float* __restrict__ g, const float* __restrict__ beta,
    int M, int C, float* __restrict__ scale, float* __restrict__ shift)
{
    int c = threadIdx.x;
    if (c >= C) return;
    float invM = 1.0f / (float)M;
    float mean = sum[c] * invM;
    float var = fmaxf(sumsq[c] * invM - mean * mean, 0.0f);
    float rstd = 1.0f / sqrtf(var + 1e-5f);
    float sc = g[c] * rstd;
    scale[c] = sc;
    shift[c] = beta[c] - mean * sc;
}

__global__ __launch_bounds__(256) void bnrelu_kernel(
    float* __restrict__ X, int total, int C,
    const float* __restrict__ scale, const float* __restrict__ shift)
{
    int i = blockIdx.x * 256 + threadIdx.x;
    if (i >= total) return;
    int c = i & (C - 1);
    X[i] = fmaxf(X[i] * scale[c] + shift[c], 0.0f);
}

// ---------------------------------------------------------------------------
extern "C" void kernel_launch(void* const* d_in, const int* in_sizes, int n_in,
                              void* d_out, int out_size, void* d_ws, size_t ws_size,
                              hipStream_t stream) {
    const float* xyz1    = (const float*)d_in[0];
    const float* xyz2    = (const float*)d_in[1];
    const float* points1 = (const float*)d_in[2];
    const float* points2 = (const float*)d_in[3];
    const float* W1      = (const float*)d_in[4];
    const float* b1      = (const float*)d_in[5];
    const float* g1      = (const float*)d_in[6];
    const float* beta1   = (const float*)d_in[7];
    const float* W2      = (const float*)d_in[8];
    const float* b2      = (const float*)d_in[9];
    const float* g2      = (const float*)d_in[10];
    const float* beta2   = (const float*)d_in[11];
    float* out = (float*)d_out;

    // ws layout (16B-aligned chunks)
    char* ws = (char*)d_ws;
    int*   idx = (int*)ws;                                 // MTOT*3
    float* w   = (float*)(ws + (size_t)MTOT*3*4);          // MTOT*3
    float* P2  = (float*)(ws + (size_t)MTOT*6*4);          // B*S*C1
    float* y1  = P2 + (size_t)BB*SS*C1;                    // MTOT*C1
    float* stats = y1 + (size_t)MTOT*C1;                   // 2048 floats
    float* sum1 = stats;            // 256
    float* sq1  = stats + 256;      // 256
    float* sum2 = stats + 512;      // 128
    float* sq2  = stats + 640;      // 128
    float* scale1 = stats + 768;    // 256
    float* shift1 = stats + 1024;   // 256
    float* scale2 = stats + 1280;   // 128
    float* shift2 = stats + 1408;   // 128
    float4* packed = (float4*)(stats + 2048);              // B*S float4
    _Float16* W1c = (_Float16*)(packed + (size_t)BB*SS);
    _Float16* W2c = W1c + (size_t)C1*(D1+D2);

    // knn partials alias y1 (y1 written later in stream order)
    float* pdist = y1;                                     // MTOT*NCH*3
    int*   pidx  = (int*)(y1 + (size_t)MTOT*NCH*3);        // MTOT*NCH*3

    hipMemsetAsync(stats, 0, 768 * sizeof(float), stream);

    pack_kernel<<<(BB*SS)/256, 256, 0, stream>>>(xyz2, packed);
    wcvt_kernel<<<(C1*(D1+D2))/256, 256, 0, stream>>>(W1, W2, W1c, W2c);

    knn3_partial_kernel<<<BB * (NN/(256*QPT)) * NCH, 256, 0, stream>>>(
        xyz1, packed, pdist, pidx);
    knn3_merge_kernel<<<MTOT/256, 256, 0, stream>>>(pdist, pidx, idx, w);

    // P2 = points2 @ W1[:,128:]^T   [B*S x 256], K=256
    gemm_mfma_kernel<256, false, false, false><<<dim3((BB*SS)/64, C1/128), 256, 0, stream>>>(
        points2, D2, W1c + D1, D1 + D2, P2, C1,
        nullptr, nullptr, nullptr, nullptr, nullptr, nullptr, nullptr, nullptr);

    // y1 = points1 @ W1[:,:128]^T + b1 + interp;  fused BN1 stats
    gemm_mfma_kernel<128, false, true, true><<<dim3(MTOT/64, C1/128), 256, 0, stream>>>(
        points1, D1, W1c, D1 + D2, y1, C1,
        b1, nullptr, nullptr, P2, idx, w, sum1, sq1);

    finalize_kernel<<<1, 256, 0, stream>>>(sum1, sq1, g1, beta1, MTOT, C1, scale1, shift1);

    // out = relu(bn1(y1)) @ W2^T + b2;  fused BN2 stats
    gemm_mfma_kernel<256, true, false, true><<<dim3(MTOT/64, C2/128), 256, 0, stream>>>(
        y1, C1, W2c, C1, out, C2,
        b2, scale1, shift1, nullptr, nullptr, nullptr, sum2, sq2);

    finalize_kernel<<<1, 128, 0, stream>>>(sum2, sq2, g2, beta2, MTOT, C2, scale2, shift2);
    bnrelu_kernel<<<(MTOT*C2)/256, 256, 0, stream>>>(out, MTOT*C2, C2, scale2, shift2);
}